// Round 10
// baseline (337.746 us; speedup 1.0000x reference)
//
#include <hip/hip_runtime.h>
#include <math.h>

#define N_POOLED (8*64*64*64)
#define N_X2     (8*128*64*64)
#define N_PARTIAL (8*32*8*128)
#define N_WT1    (588*64)
#define N_WT2    (576*128)

// ---- k_wt: transpose weights to [k][oc] (k-major) for LDS slab staging ----
// wT1[k*64  + oc], k = ic*49 + ky*7 + kx
// wT2[k*128 + oc], k = ic*9 + tap
__global__ void k_wt(const float* __restrict__ w1, const float* __restrict__ w2,
                     float* __restrict__ wT1, float* __restrict__ wT2) {
    int idx = blockIdx.x * 256 + threadIdx.x;   // 435*256 = 111360 exact
    if (idx < 37632) {
        int oc = idx & 63;
        int k  = idx >> 6;
        wT1[idx] = w1[oc * 588 + k];
    } else {
        int j = idx - 37632;                    // < 73728
        int oc = j & 127;
        int k  = j >> 7;
        wT2[j] = w2[oc * 576 + k];
    }
}

// -------------------------------------------------------------------------
// k1: conv1 7x7 pad3 (12->64) + bias + ReLU + maxpool2x2 -> pooled[8][64][64][64]
// grid 2048 = b(8, XCD pin) x ocg(4: 16 oc) x tile(64: 16x16 px), 5 blocks/CU.
// Weights staged in LDS per phase (broadcast ds_read_b128) -> pure-DS lgkm
// stream (in-order) so the compiler can count lgkmcnt finely; no SMEM in loop.
// per thread: 2x2 conv px x 4 oc, rolling fr[2][8].
// -------------------------------------------------------------------------
__global__ __launch_bounds__(256, 5) void k_conv1_pool(
    const float* __restrict__ images, const float* __restrict__ wT1,
    const float* __restrict__ b1, float* __restrict__ pooled)
{
    __shared__ float in_t[6 * 22 * 24];    // 12672 B
    __shared__ float w_t[294 * 16];        // 18816 B: [icl*49+ky*7+kx][16 oc]
    const int tid = threadIdx.x;
    const int bid = blockIdx.x;
    const int b    = bid & 7;
    const int rest = bid >> 3;
    const int ocg  = rest & 3;
    const int tile = rest >> 2;            // 0..63
    const int R0 = (tile >> 3) * 16;
    const int C0 = (tile & 7) * 16;

    const int waveU = __builtin_amdgcn_readfirstlane(tid >> 6);
    const int lane  = tid & 63;
    const int py0   = (lane >> 3) * 2;
    const int px0   = (lane & 7) * 2;
    const int ocf0  = ocg * 16 + waveU * 4;

    const float* p  = &in_t[py0 * 24 + px0];
    const float* wb0 = &w_t[waveU * 4];    // + (icl*49+ky*7+kx)*16, imm offsets

    float acc[4][4];
    #pragma unroll
    for (int oc = 0; oc < 4; ++oc)
        #pragma unroll
        for (int q = 0; q < 4; ++q) acc[oc][q] = 0.0f;

    #pragma unroll 1
    for (int phase = 0; phase < 2; ++phase) {
        if (phase) __syncthreads();        // compute of prev phase done
        // stage 6 ic of input: rows R0-3..R0+18, cols C0-3..C0+18, zero-pad
        for (int idx = tid; idx < 6 * 22 * 22; idx += 256) {
            int icl = idx / 484;
            int rem = idx - icl * 484;
            int r   = rem / 22;
            int c   = rem - r * 22;
            int gr = R0 - 3 + r, gc = C0 - 3 + c;
            float v = 0.0f;
            if ((unsigned)gr < 128u && (unsigned)gc < 128u)
                v = images[((b * 12 + phase * 6 + icl) * 128 + gr) * 128 + gc];
            in_t[(icl * 22 + r) * 24 + c] = v;
        }
        // stage this phase's 16-oc weight slab: 294 k-rows x 16 oc
        for (int idx = tid; idx < 294 * 16; idx += 256) {
            int ocl = idx & 15;
            int row = idx >> 4;            // icl*49 + ky*7 + kx
            w_t[idx] = wT1[(phase * 294 + row) * 64 + ocg * 16 + ocl];
        }
        __syncthreads();

        #pragma unroll 1
        for (int icl = 0; icl < 6; ++icl) {
            const float* base = p + icl * 528;       // 22*24
            const float* wbi  = wb0 + icl * 49 * 16;
            float fr[2][8];
            #pragma unroll
            for (int h = 0; h < 2; ++h)
                #pragma unroll
                for (int j2 = 0; j2 < 4; ++j2) {
                    float2 t = *(const float2*)(base + h * 24 + 2 * j2);
                    fr[h][2 * j2] = t.x; fr[h][2 * j2 + 1] = t.y;
                }
            #pragma unroll
            for (int ky = 0; ky < 7; ++ky) {
                #pragma unroll
                for (int kx = 0; kx < 7; ++kx) {
                    // broadcast read: all 64 lanes same address
                    const float4 wq = *(const float4*)(wbi + (ky * 7 + kx) * 16);
                    const float wv[4] = {wq.x, wq.y, wq.z, wq.w};
                    #pragma unroll
                    for (int oc = 0; oc < 4; ++oc) {
                        float w = wv[oc];
                        acc[oc][0] = fmaf(fr[ky & 1][kx],           w, acc[oc][0]);
                        acc[oc][1] = fmaf(fr[ky & 1][kx + 1],       w, acc[oc][1]);
                        acc[oc][2] = fmaf(fr[(ky + 1) & 1][kx],     w, acc[oc][2]);
                        acc[oc][3] = fmaf(fr[(ky + 1) & 1][kx + 1], w, acc[oc][3]);
                    }
                }
                if (ky < 6) {   // roll in row py0+ky+2
                    #pragma unroll
                    for (int j2 = 0; j2 < 4; ++j2) {
                        float2 t = *(const float2*)(base + (ky + 2) * 24 + 2 * j2);
                        fr[ky & 1][2 * j2] = t.x; fr[ky & 1][2 * j2 + 1] = t.y;
                    }
                }
            }
        }
    }

    // bias + ReLU + 2x2 maxpool: 2x2 conv px == one pooled px
    const int ph = (R0 + py0) >> 1;
    const int pw = (C0 + px0) >> 1;
    #pragma unroll
    for (int oc = 0; oc < 4; ++oc) {
        float bias = b1[ocf0 + oc];
        float m = fmaxf(fmaxf(acc[oc][0], acc[oc][1]), fmaxf(acc[oc][2], acc[oc][3]));
        pooled[((b * 64 + ocf0 + oc) * 64 + ph) * 64 + pw] = fmaxf(m + bias, 0.0f);
    }
}

// -------------------------------------------------------------------------
// k2: conv2 3x3 pad1 (64->128) + bias + ReLU + pos-emb -> x2[8][128][64][64]
// grid 1024 = b(8) x ocg(8: 16 oc) x tile(16); weights via LDS broadcast.
// -------------------------------------------------------------------------
__global__ __launch_bounds__(256, 4) void k_conv2_emb(
    const float* __restrict__ pooled, const float* __restrict__ wT2,
    const float* __restrict__ b2, const float* __restrict__ pew,
    const float* __restrict__ peb, float* __restrict__ x2)
{
    __shared__ float in_t[16 * 18 * 24];   // 27648 B
    __shared__ float w_t[144 * 16];        // 9216 B: [icl*9+tap][16 oc]
    const int tid = threadIdx.x;
    const int bid = blockIdx.x;
    const int b    = bid & 7;
    const int rest = bid >> 3;
    const int ocg  = rest & 7;
    const int tile = rest >> 3;            // 0..15
    const int R0 = (tile >> 2) * 16;
    const int C0 = (tile & 3) * 16;

    const int waveU = __builtin_amdgcn_readfirstlane(tid >> 6);
    const int lane  = tid & 63;
    const int py0   = (lane >> 3) * 2;
    const int px0   = (lane & 7) * 2;
    const int ocf0  = ocg * 16 + waveU * 4;

    const float* p   = &in_t[py0 * 24 + px0];
    const float* wb0 = &w_t[waveU * 4];

    float acc[4][4];
    #pragma unroll
    for (int oc = 0; oc < 4; ++oc)
        #pragma unroll
        for (int q = 0; q < 4; ++q) acc[oc][q] = 0.0f;

    #pragma unroll 1
    for (int chunk = 0; chunk < 4; ++chunk) {
        __syncthreads();
        for (int idx = tid; idx < 16 * 18 * 18; idx += 256) {
            int icl = idx / 324;
            int rem = idx - icl * 324;
            int r   = rem / 18;
            int c   = rem - r * 18;
            int gr = R0 - 1 + r, gc = C0 - 1 + c;
            float v = 0.0f;
            if ((unsigned)gr < 64u && (unsigned)gc < 64u)
                v = pooled[((b * 64 + chunk * 16 + icl) * 64 + gr) * 64 + gc];
            in_t[(icl * 18 + r) * 24 + c] = v;
        }
        for (int idx = tid; idx < 144 * 16; idx += 256) {
            int ocl = idx & 15;
            int row = idx >> 4;            // icl*9 + tap
            w_t[idx] = wT2[(chunk * 144 + row) * 128 + ocg * 16 + ocl];
        }
        __syncthreads();

        #pragma unroll 1
        for (int icl = 0; icl < 16; ++icl) {
            float fr[4][4];
            #pragma unroll
            for (int h = 0; h < 4; ++h)
                #pragma unroll
                for (int j2 = 0; j2 < 2; ++j2) {
                    float2 t = *(const float2*)(p + icl * 432 + h * 24 + 2 * j2);
                    fr[h][2 * j2] = t.x; fr[h][2 * j2 + 1] = t.y;
                }
            const float* wbi = wb0 + icl * 9 * 16;
            #pragma unroll
            for (int ky = 0; ky < 3; ++ky)
                #pragma unroll
                for (int kx = 0; kx < 3; ++kx) {
                    const float4 wq = *(const float4*)(wbi + (ky * 3 + kx) * 16);
                    const float wv[4] = {wq.x, wq.y, wq.z, wq.w};
                    #pragma unroll
                    for (int oc = 0; oc < 4; ++oc) {
                        float w = wv[oc];
                        acc[oc][0] = fmaf(fr[ky][kx],         w, acc[oc][0]);
                        acc[oc][1] = fmaf(fr[ky][kx + 1],     w, acc[oc][1]);
                        acc[oc][2] = fmaf(fr[ky + 1][kx],     w, acc[oc][2]);
                        acc[oc][3] = fmaf(fr[ky + 1][kx + 1], w, acc[oc][3]);
                    }
                }
        }
    }

    // bias + ReLU + soft position embedding (grid value = i/63)
    const float inv63 = 1.0f / 63.0f;
    #pragma unroll
    for (int oc = 0; oc < 4; ++oc) {
        int ocf = ocf0 + oc;
        float bias = b2[ocf];
        float e0 = pew[ocf * 4 + 0], e1 = pew[ocf * 4 + 1];
        float e2 = pew[ocf * 4 + 2], e3 = pew[ocf * 4 + 3];
        float pb = peb[ocf];
        #pragma unroll
        for (int di = 0; di < 2; ++di) {
            int gh = R0 + py0 + di;
            float y = (float)gh * inv63;
            float rowc = pb + y * e0 + (1.0f - y) * e2;
            int gw = C0 + px0;
            float xq0 = (float)gw * inv63;
            float xq1 = (float)(gw + 1) * inv63;
            float2 st;
            st.x = fmaxf(acc[oc][di * 2 + 0] + bias, 0.0f) + rowc + xq0 * e1 + (1.0f - xq0) * e3;
            st.y = fmaxf(acc[oc][di * 2 + 1] + bias, 0.0f) + rowc + xq1 * e1 + (1.0f - xq1) * e3;
            *(float2*)&x2[((b * 128 + ocf) * 64 + gh) * 64 + gw] = st;
        }
    }
}

// -------------------------------------------------------------------------
// k3: masked spatial max partials. (unchanged from R9)
// grid 1024 = b(8) x og(2: 16 obj) x pe(8: 512 px) x cg(8: 16 ch)
// -------------------------------------------------------------------------
__global__ __launch_bounds__(256, 4) void k_roi(
    const float* __restrict__ x2, const int* __restrict__ rois,
    float* __restrict__ partial)
{
    __shared__ float mlds[16 * 512];       // 32 KB
    const int tid = threadIdx.x;
    const int bid = blockIdx.x;
    const int b    = bid & 7;
    const int rest = bid >> 3;
    const int og   = rest & 1;
    const int pe   = (rest >> 1) & 7;
    const int cg   = rest >> 4;            // 0..7

    for (int idx = tid; idx < 16 * 512; idx += 256) {
        int ol = idx >> 9;
        int pp = idx & 511;
        int px = pe * 512 + pp;
        int h = px >> 6, w = px & 63;
        mlds[idx] = rois[((b * 32 + og * 16 + ol) << 14) + (h << 8) + (w << 1)] ? 1.0f : 0.0f;
    }
    __syncthreads();

    const int waveU = __builtin_amdgcn_readfirstlane(tid >> 6);
    const int lane  = tid & 63;
    const int c0    = cg * 16 + waveU * 4;

    float acc[4][16];
    #pragma unroll
    for (int c = 0; c < 4; ++c)
        #pragma unroll
        for (int o = 0; o < 16; ++o) acc[c][o] = -INFINITY;

    #pragma unroll 1
    for (int step = 0; step < 8; ++step) {
        int pp = step * 64 + lane;
        float m[16];
        #pragma unroll
        for (int o = 0; o < 16; ++o) m[o] = mlds[o * 512 + pp];
        const float* xb = &x2[(b * 128 + c0) * 4096 + pe * 512 + pp];
        #pragma unroll
        for (int c = 0; c < 4; ++c) {
            float x = xb[c * 4096];
            #pragma unroll
            for (int o = 0; o < 16; ++o)
                acc[c][o] = fmaxf(acc[c][o], x * m[o]);
        }
    }

    #pragma unroll
    for (int c = 0; c < 4; ++c)
        #pragma unroll
        for (int o = 0; o < 16; ++o) {
            float v = acc[c][o];
            #pragma unroll
            for (int mm = 1; mm < 64; mm <<= 1)
                v = fmaxf(v, __shfl_xor(v, mm, 64));
            if (lane == o * 4 + c)
                partial[((b * 32 + og * 16 + o) * 8 + pe) * 128 + c0 + c] = v;
        }
}

// k4: reduce the 8 pixel-chunk partials -> out[8][32][128]
__global__ void k_reduce(const float* __restrict__ partial, float* __restrict__ out) {
    int idx = blockIdx.x * 256 + threadIdx.x;   // 32768
    int c  = idx & 127;
    int bo = idx >> 7;
    float v = partial[bo * 8 * 128 + c];
    #pragma unroll
    for (int pe = 1; pe < 8; ++pe)
        v = fmaxf(v, partial[(bo * 8 + pe) * 128 + c]);
    out[idx] = v;
}

extern "C" void kernel_launch(void* const* d_in, const int* in_sizes, int n_in,
                              void* d_out, int out_size, void* d_ws, size_t ws_size,
                              hipStream_t stream) {
    const float* images = (const float*)d_in[0];
    const int*   rois   = (const int*)d_in[1];
    // d_in[2] = gt_pos (unused)
    const float* w1  = (const float*)d_in[3];
    const float* b1  = (const float*)d_in[4];
    const float* w2  = (const float*)d_in[5];
    const float* b2  = (const float*)d_in[6];
    const float* pew = (const float*)d_in[7];
    const float* peb = (const float*)d_in[8];
    float* out = (float*)d_out;

    float* pooled  = (float*)d_ws;
    float* x2      = pooled  + N_POOLED;
    float* partial = x2      + N_X2;
    float* wT1     = partial + N_PARTIAL;
    float* wT2     = wT1     + N_WT1;

    k_wt<<<435, 256, 0, stream>>>(w1, w2, wT1, wT2);
    k_conv1_pool<<<2048, 256, 0, stream>>>(images, wT1, b1, pooled);
    k_conv2_emb<<<1024, 256, 0, stream>>>(pooled, wT2, b2, pew, peb, x2);
    k_roi<<<1024, 256, 0, stream>>>(x2, rois, partial);
    k_reduce<<<128, 256, 0, stream>>>(partial, out);
}

// Round 11
// 200.964 us; speedup vs baseline: 1.6806x; 1.6806x over previous
//
#include <hip/hip_runtime.h>
#include <math.h>

typedef __attribute__((ext_vector_type(8))) short bf16x8;
typedef __attribute__((ext_vector_type(4))) float f32x4;
typedef __attribute__((ext_vector_type(8))) unsigned short ushort8;

#define N_IMT  (8*136*136*16)     // imTp: [b][136r][136c][16ch] bf16 (hi or lo)
#define N_PT   (8*66*66*64)       // poolTp: [b][66][66][64] bf16
#define N_X2   (8*128*64*64)
#define N_PARTIAL (8*32*8*128)
#define N_WB1  (25*4*64*8)        // 51200 per split
#define N_WB2  (18*8*64*8)        // 73728 per split

__device__ inline unsigned short f2bf(float f) {
    unsigned u = __float_as_uint(f);
    u += 0x7FFF + ((u >> 16) & 1);          // RNE
    return (unsigned short)(u >> 16);
}
__device__ inline float bf2f(unsigned short h) {
    return __uint_as_float(((unsigned)h) << 16);
}

// ---- k_zero: zero imTp_hi/lo + poolTp_hi/lo (borders + pad channels) ----
__global__ void k_zero(unsigned* __restrict__ p, int n) {
    int stride = gridDim.x * 256;
    for (int i = blockIdx.x * 256 + threadIdx.x; i < n; i += stride) p[i] = 0u;
}

// ---- k_prep: transpose/split images -> imTp; pack weights -> per-frag slabs ----
// blocks 0..511: imTp interior; 512..536: wB1; 537..572: wB2
__global__ void k_prep(const float* __restrict__ images,
                       const float* __restrict__ w1, const float* __restrict__ w2,
                       unsigned short* __restrict__ imTh, unsigned short* __restrict__ imTl,
                       unsigned short* __restrict__ wB1h, unsigned short* __restrict__ wB1l,
                       unsigned short* __restrict__ wB2h, unsigned short* __restrict__ wB2l)
{
    const int bid = blockIdx.x, tid = threadIdx.x;
    if (bid < 512) {
        int t = bid * 256 + tid;              // (b,y,x) over 8*128*128
        int b = t >> 14, rem = t & 16383;
        int y = rem >> 7, x = rem & 127;
        ushort8 h0, h1, l0, l1;
        #pragma unroll
        for (int j = 0; j < 8; ++j) {
            float v = images[((b * 12 + j) << 14) + (y << 7) + x];
            unsigned short h = f2bf(v);
            h0[j] = h; l0[j] = f2bf(v - bf2f(h));
        }
        #pragma unroll
        for (int j = 0; j < 4; ++j) {
            float v = images[((b * 12 + 8 + j) << 14) + (y << 7) + x];
            unsigned short h = f2bf(v);
            h1[j] = h; l1[j] = f2bf(v - bf2f(h));
        }
        #pragma unroll
        for (int j = 4; j < 8; ++j) { h1[j] = 0; l1[j] = 0; }
        int base = ((b * 136 + y + 3) * 136 + x + 3) * 16;
        *(ushort8*)(imTh + base) = h0;  *(ushort8*)(imTh + base + 8) = h1;
        *(ushort8*)(imTl + base) = l0;  *(ushort8*)(imTl + base + 8) = l1;
    } else if (bid < 537) {
        // wB1[s][n][lane][8]: oc=n*16+(l&15); g=l>>4; tap=2s+(g>>1); ic=(g&1)*8+j
        int s = bid - 512;
        int n = tid >> 6, l = tid & 63;
        int oc = n * 16 + (l & 15), g = l >> 4;
        int tap = 2 * s + (g >> 1);
        ushort8 hi, lo;
        #pragma unroll
        for (int j = 0; j < 8; ++j) {
            int ic = (g & 1) * 8 + j;
            float v = (tap < 49 && ic < 12) ? w1[oc * 588 + ic * 49 + tap] : 0.0f;
            unsigned short h = f2bf(v);
            hi[j] = h; lo[j] = f2bf(v - bf2f(h));
        }
        int idx = ((s * 4 + n) * 64 + l) * 8;
        *(ushort8*)(wB1h + idx) = hi;  *(ushort8*)(wB1l + idx) = lo;
    } else {
        // wB2[s][n][lane][8]: tap=s>>1; ic=(s&1)*32+(l>>4)*8+j
        int u = bid - 537;
        int s = u >> 1, nh = u & 1;
        int n = nh * 4 + (tid >> 6), l = tid & 63;
        int oc = n * 16 + (l & 15);
        int tap = s >> 1;
        ushort8 hi, lo;
        #pragma unroll
        for (int j = 0; j < 8; ++j) {
            int ic = (s & 1) * 32 + (l >> 4) * 8 + j;
            float v = w2[oc * 576 + ic * 9 + tap];
            unsigned short h = f2bf(v);
            hi[j] = h; lo[j] = f2bf(v - bf2f(h));
        }
        int idx = ((s * 8 + n) * 64 + l) * 8;
        *(ushort8*)(wB2h + idx) = hi;  *(ushort8*)(wB2l + idx) = lo;
    }
}

// -------------------------------------------------------------------------
// k1: conv1 7x7 (12->64) + bias + ReLU + maxpool via MFMA implicit GEMM.
// grid 1024 = b(8) x y0(64 pooled rows) x xh(2). Block: conv rows {2y0,2y0+1}
// x 64 cols x 64 oc. Wave w: 16-col strip, both rows (M-frags) x 4 n-tiles.
// K = 25 steps x 32 (2 taps x 16 ic-padded). 3-product bf16 split.
// A: imTp[row][col][ch] -> lane(l&15)=px, (l>>4)=g: tap parity g>>1, ic-half g&1.
// -------------------------------------------------------------------------
__global__ __launch_bounds__(256, 4) void k1_mfma(
    const unsigned short* __restrict__ imTh, const unsigned short* __restrict__ imTl,
    const unsigned short* __restrict__ wB1h, const unsigned short* __restrict__ wB1l,
    const float* __restrict__ b1,
    unsigned short* __restrict__ pTh, unsigned short* __restrict__ pTl)
{
    const int bid = blockIdx.x;
    const int b  = bid & 7;
    const int rest = bid >> 3;
    const int y0 = rest & 63;
    const int x0 = (rest >> 6) * 64;
    const int tid = threadIdx.x;
    const int w  = __builtin_amdgcn_readfirstlane(tid >> 6);
    const int l  = tid & 63;
    const int px = l & 15;
    const int g  = l >> 4;
    const int gq = g >> 1;                  // tap parity
    const int baseA = ((b * 136 + 2 * y0) * 136 + (x0 + w * 16 + px)) * 16 + (g & 1) * 8;

    f32x4 acc[2][4];
    #pragma unroll
    for (int m = 0; m < 2; ++m)
        #pragma unroll
        for (int n = 0; n < 4; ++n) acc[m][n] = (f32x4)(0.0f);

    #pragma unroll
    for (int s = 0; s < 25; ++s) {
        const int t0 = 2 * s, t1 = 2 * s + 1;
        const int off0 = ((t0 / 7) * 136 + (t0 % 7)) * 16;
        const int off1 = ((t1 / 7) * 136 + (t1 % 7)) * 16;
        int offA = gq ? off1 : off0;
        bf16x8 Ah0 = *(const bf16x8*)(imTh + baseA + offA);
        bf16x8 Ah1 = *(const bf16x8*)(imTh + baseA + 2176 + offA);   // +136*16
        bf16x8 Al0 = *(const bf16x8*)(imTl + baseA + offA);
        bf16x8 Al1 = *(const bf16x8*)(imTl + baseA + 2176 + offA);
        const unsigned short* wb = wB1h + s * 2048 + l * 8;
        const unsigned short* wl2 = wB1l + s * 2048 + l * 8;
        #pragma unroll
        for (int n = 0; n < 4; ++n) {
            bf16x8 Bh = *(const bf16x8*)(wb + n * 512);
            bf16x8 Bl = *(const bf16x8*)(wl2 + n * 512);
            acc[0][n] = __builtin_amdgcn_mfma_f32_16x16x32_bf16(Ah0, Bh, acc[0][n], 0, 0, 0);
            acc[0][n] = __builtin_amdgcn_mfma_f32_16x16x32_bf16(Ah0, Bl, acc[0][n], 0, 0, 0);
            acc[0][n] = __builtin_amdgcn_mfma_f32_16x16x32_bf16(Al0, Bh, acc[0][n], 0, 0, 0);
            acc[1][n] = __builtin_amdgcn_mfma_f32_16x16x32_bf16(Ah1, Bh, acc[1][n], 0, 0, 0);
            acc[1][n] = __builtin_amdgcn_mfma_f32_16x16x32_bf16(Ah1, Bl, acc[1][n], 0, 0, 0);
            acc[1][n] = __builtin_amdgcn_mfma_f32_16x16x32_bf16(Al1, Bh, acc[1][n], 0, 0, 0);
        }
    }

    // epilogue: bias + maxpool(2x2) + ReLU, write bf16 hi/lo into poolTp
    // C layout: col(oc-local)=l&15, row(px in strip)=g*4+e
    #pragma unroll
    for (int n = 0; n < 4; ++n) {
        int oc = n * 16 + px;
        float bias = b1[oc];
        #pragma unroll
        for (int pp = 0; pp < 2; ++pp) {
            int e = pp * 2;
            float m = fmaxf(fmaxf(acc[0][n][e], acc[0][n][e + 1]),
                            fmaxf(acc[1][n][e], acc[1][n][e + 1]));
            float v = fmaxf(m + bias, 0.0f);
            unsigned short h = f2bf(v);
            unsigned short lo = f2bf(v - bf2f(h));
            int pcol = (x0 >> 1) + w * 8 + g * 2 + pp;       // 0..63
            int pidx = ((b * 66 + y0 + 1) * 66 + pcol + 1) * 64 + oc;
            pTh[pidx] = h; pTl[pidx] = lo;
        }
    }
}

// -------------------------------------------------------------------------
// k2: conv2 3x3 (64->128) + bias + ReLU + pos-emb via MFMA implicit GEMM.
// grid 1024 = b(8) x y(64 rows) x ocg(2: 64 oc). Wave w: 16-col strip x 4 n-tiles.
// K = 18 steps x 32 (tap x 32-ic half). 3-product bf16 split. Output f32 x2.
// -------------------------------------------------------------------------
__global__ __launch_bounds__(256, 4) void k2_mfma(
    const unsigned short* __restrict__ pTh, const unsigned short* __restrict__ pTl,
    const unsigned short* __restrict__ wB2h, const unsigned short* __restrict__ wB2l,
    const float* __restrict__ b2, const float* __restrict__ pew,
    const float* __restrict__ peb, float* __restrict__ x2)
{
    const int bid = blockIdx.x;
    const int b   = bid & 7;
    const int rest = bid >> 3;
    const int y   = rest & 63;
    const int ocg = rest >> 6;              // 0..1
    const int tid = threadIdx.x;
    const int w  = __builtin_amdgcn_readfirstlane(tid >> 6);
    const int l  = tid & 63;
    const int px = l & 15;
    const int g  = l >> 4;
    const int baseA = ((b * 66 + y) * 66 + (w * 16 + px)) * 64 + g * 8;

    f32x4 acc[4];
    #pragma unroll
    for (int n = 0; n < 4; ++n) acc[n] = (f32x4)(0.0f);

    #pragma unroll
    for (int s = 0; s < 18; ++s) {
        const int tap = s >> 1;
        const int offA = ((tap / 3) * 66 + (tap % 3)) * 64 + (s & 1) * 32;
        bf16x8 Ah = *(const bf16x8*)(pTh + baseA + offA);
        bf16x8 Al = *(const bf16x8*)(pTl + baseA + offA);
        const unsigned short* wb = wB2h + s * 4096 + (ocg * 4) * 512 + l * 8;
        const unsigned short* wl2 = wB2l + s * 4096 + (ocg * 4) * 512 + l * 8;
        #pragma unroll
        for (int n = 0; n < 4; ++n) {
            bf16x8 Bh = *(const bf16x8*)(wb + n * 512);
            bf16x8 Bl = *(const bf16x8*)(wl2 + n * 512);
            acc[n] = __builtin_amdgcn_mfma_f32_16x16x32_bf16(Ah, Bh, acc[n], 0, 0, 0);
            acc[n] = __builtin_amdgcn_mfma_f32_16x16x32_bf16(Ah, Bl, acc[n], 0, 0, 0);
            acc[n] = __builtin_amdgcn_mfma_f32_16x16x32_bf16(Al, Bh, acc[n], 0, 0, 0);
        }
    }

    // epilogue: bias + ReLU + position embedding (grid value = i/63), f32 store
    const float inv63 = 1.0f / 63.0f;
    float yn = (float)y * inv63;
    #pragma unroll
    for (int n = 0; n < 4; ++n) {
        int oc = ocg * 64 + n * 16 + px;
        float bias = b2[oc];
        float e0 = pew[oc * 4 + 0], e1 = pew[oc * 4 + 1];
        float e2 = pew[oc * 4 + 2], e3 = pew[oc * 4 + 3];
        float rowc = peb[oc] + yn * e0 + (1.0f - yn) * e2;
        f32x4 st;
        #pragma unroll
        for (int e = 0; e < 4; ++e) {
            int x = w * 16 + g * 4 + e;
            float xn = (float)x * inv63;
            st[e] = fmaxf(acc[n][e] + bias, 0.0f) + rowc + xn * e1 + (1.0f - xn) * e3;
        }
        *(f32x4*)&x2[((b * 128 + oc) * 64 + y) * 64 + w * 16 + g * 4] = st;
    }
}

// -------------------------------------------------------------------------
// k3: masked spatial max partials. (unchanged from R9)
// grid 1024 = b(8) x og(2: 16 obj) x pe(8: 512 px) x cg(8: 16 ch)
// -------------------------------------------------------------------------
__global__ __launch_bounds__(256, 4) void k_roi(
    const float* __restrict__ x2, const int* __restrict__ rois,
    float* __restrict__ partial)
{
    __shared__ float mlds[16 * 512];
    const int tid = threadIdx.x;
    const int bid = blockIdx.x;
    const int b    = bid & 7;
    const int rest = bid >> 3;
    const int og   = rest & 1;
    const int pe   = (rest >> 1) & 7;
    const int cg   = rest >> 4;

    for (int idx = tid; idx < 16 * 512; idx += 256) {
        int ol = idx >> 9;
        int pp = idx & 511;
        int pxx = pe * 512 + pp;
        int h = pxx >> 6, ww = pxx & 63;
        mlds[idx] = rois[((b * 32 + og * 16 + ol) << 14) + (h << 8) + (ww << 1)] ? 1.0f : 0.0f;
    }
    __syncthreads();

    const int waveU = __builtin_amdgcn_readfirstlane(tid >> 6);
    const int lane  = tid & 63;
    const int c0    = cg * 16 + waveU * 4;

    float acc[4][16];
    #pragma unroll
    for (int c = 0; c < 4; ++c)
        #pragma unroll
        for (int o = 0; o < 16; ++o) acc[c][o] = -INFINITY;

    #pragma unroll 1
    for (int step = 0; step < 8; ++step) {
        int pp = step * 64 + lane;
        float m[16];
        #pragma unroll
        for (int o = 0; o < 16; ++o) m[o] = mlds[o * 512 + pp];
        const float* xb = &x2[(b * 128 + c0) * 4096 + pe * 512 + pp];
        #pragma unroll
        for (int c = 0; c < 4; ++c) {
            float x = xb[c * 4096];
            #pragma unroll
            for (int o = 0; o < 16; ++o)
                acc[c][o] = fmaxf(acc[c][o], x * m[o]);
        }
    }

    #pragma unroll
    for (int c = 0; c < 4; ++c)
        #pragma unroll
        for (int o = 0; o < 16; ++o) {
            float v = acc[c][o];
            #pragma unroll
            for (int mm = 1; mm < 64; mm <<= 1)
                v = fmaxf(v, __shfl_xor(v, mm, 64));
            if (lane == o * 4 + c)
                partial[((b * 32 + og * 16 + o) * 8 + pe) * 128 + c0 + c] = v;
        }
}

// k4: reduce the 8 pixel-chunk partials -> out[8][32][128]
__global__ void k_reduce(const float* __restrict__ partial, float* __restrict__ out) {
    int idx = blockIdx.x * 256 + threadIdx.x;   // 32768
    int c  = idx & 127;
    int bo = idx >> 7;
    float v = partial[bo * 8 * 128 + c];
    #pragma unroll
    for (int pe = 1; pe < 8; ++pe)
        v = fmaxf(v, partial[(bo * 8 + pe) * 128 + c]);
    out[idx] = v;
}

extern "C" void kernel_launch(void* const* d_in, const int* in_sizes, int n_in,
                              void* d_out, int out_size, void* d_ws, size_t ws_size,
                              hipStream_t stream) {
    const float* images = (const float*)d_in[0];
    const int*   rois   = (const int*)d_in[1];
    // d_in[2] = gt_pos (unused)
    const float* w1  = (const float*)d_in[3];
    const float* b1  = (const float*)d_in[4];
    const float* w2  = (const float*)d_in[5];
    const float* b2  = (const float*)d_in[6];
    const float* pew = (const float*)d_in[7];
    const float* peb = (const float*)d_in[8];
    float* out = (float*)d_out;

    unsigned short* imTh = (unsigned short*)d_ws;
    unsigned short* imTl = imTh + N_IMT;
    unsigned short* pTh  = imTl + N_IMT;
    unsigned short* pTl  = pTh  + N_PT;
    float* x2      = (float*)(pTl + N_PT);
    float* partial = x2 + N_X2;
    unsigned short* wB1h = (unsigned short*)(partial + N_PARTIAL);
    unsigned short* wB1l = wB1h + N_WB1;
    unsigned short* wB2h = wB1l + N_WB1;
    unsigned short* wB2l = wB2h + N_WB2;

    const int nzero = (2 * N_IMT + 2 * N_PT) / 2;   // u32 count
    k_zero<<<2048, 256, 0, stream>>>((unsigned*)d_ws, nzero);
    k_prep<<<573, 256, 0, stream>>>(images, w1, w2, imTh, imTl, wB1h, wB1l, wB2h, wB2l);
    k1_mfma<<<1024, 256, 0, stream>>>(imTh, imTl, wB1h, wB1l, b1, pTh, pTl);
    k2_mfma<<<1024, 256, 0, stream>>>(pTh, pTl, wB2h, wB2l, b2, pew, peb, x2);
    k_roi<<<1024, 256, 0, stream>>>(x2, rois, partial);
    k_reduce<<<128, 256, 0, stream>>>(partial, out);
}